// Round 1
// baseline (295.410 us; speedup 1.0000x reference)
//
#include <hip/hip_runtime.h>
#include <hip/hip_bf16.h>
#include <math.h>

// Problem constants: B=2, S=2048, D=1024, H=16, HD=64
typedef unsigned short ushort_t;
typedef __attribute__((ext_vector_type(8))) short short8;   // 8 bf16 = 4 VGPRs (MFMA A/B frag)
typedef __attribute__((ext_vector_type(4))) float f32x4;    // MFMA C/D frag

struct __align__(8) us4 { ushort_t u[4]; };

__device__ __forceinline__ ushort_t f2bf(float x) {
  union { float f; unsigned u; } c; c.f = x;
  unsigned r = c.u + 0x7FFFu + ((c.u >> 16) & 1u);  // RNE
  return (ushort_t)(r >> 16);
}
__device__ __forceinline__ float bf2f(ushort_t b) {
  union { unsigned u; float f; } c; c.u = ((unsigned)b) << 16;
  return c.f;
}

// ---------------------------------------------------------------------------
// fp32 -> bf16 bulk convert (X and the three W matrices)
// ---------------------------------------------------------------------------
__global__ __launch_bounds__(256) void cvt_kernel(const float* __restrict__ src,
                                                  ushort_t* __restrict__ dst, int n) {
  int i = (blockIdx.x * 256 + threadIdx.x) * 4;
  if (i < n) {
    f32x4 v = *(const f32x4*)(src + i);
    us4 o;
    o.u[0] = f2bf(v[0]); o.u[1] = f2bf(v[1]); o.u[2] = f2bf(v[2]); o.u[3] = f2bf(v[3]);
    *(us4*)(dst + i) = o;
  }
}

// ---------------------------------------------------------------------------
// QKV projection GEMM: C[m,n] = sum_k X[m,k]*W[n,k] + bias[n]
// m97 structure: 128x128 tile, BK=32, global_load_lds width=16.
// Output written bf16 directly in attention layout [(b*16+h)*2048 + s]*64 + hd.
// ---------------------------------------------------------------------------
struct QkvArgs {
  const ushort_t* X;
  const ushort_t* W0; const ushort_t* W1; const ushort_t* W2;
  const float* b0; const float* b1; const float* b2;
  ushort_t* o0; ushort_t* o1; ushort_t* o2;
};

__global__ __launch_bounds__(256) void qkv_gemm(QkvArgs a) {
  // LDS rows = 32 bf16 = 64B = 16 banks -> 2-way conflict on b128 reads (free, m136)
  __shared__ __align__(16) ushort_t As[128 * 32];
  __shared__ __align__(16) ushort_t Bs[128 * 32];
  const int z = blockIdx.z;
  const ushort_t* W  = (z == 0) ? a.W0 : ((z == 1) ? a.W1 : a.W2);
  const float* bias  = (z == 0) ? a.b0 : ((z == 1) ? a.b1 : a.b2);
  ushort_t* out      = (z == 0) ? a.o0 : ((z == 1) ? a.o1 : a.o2);
  const int mBase = blockIdx.x * 128;
  const int nBase = blockIdx.y * 128;
  const int tid  = threadIdx.x;
  const int lane = tid & 63;
  const int w    = tid >> 6;        // wave 0..3
  const int wm   = w >> 1, wn = w & 1;  // 2x2 wave grid, 64x64 each
  const int quad = lane >> 4;
  const int l15  = lane & 15;

  f32x4 acc[4][4] = {};

  // staging: lane covers row (lane>>2), 16B chunk (lane&3) of a 16-row slab
  const int srow = lane >> 2;
  const int scol = (lane & 3) * 8;
  const ushort_t* gA0 = a.X + (mBase + srow) * 1024 + scol;
  const ushort_t* gB0 = W   + (nBase + srow) * 1024 + scol;

  for (int k0 = 0; k0 < 1024; k0 += 32) {
#pragma unroll
    for (int p = 0; p < 2; ++p) {
      int rr = (w * 2 + p) * 16;
      __builtin_amdgcn_global_load_lds(
          (const __attribute__((address_space(1))) void*)(gA0 + rr * 1024 + k0),
          (__attribute__((address_space(3))) void*)(As + (w * 2 + p) * 512), 16, 0, 0);
      __builtin_amdgcn_global_load_lds(
          (const __attribute__((address_space(1))) void*)(gB0 + rr * 1024 + k0),
          (__attribute__((address_space(3))) void*)(Bs + (w * 2 + p) * 512), 16, 0, 0);
    }
    __syncthreads();
    short8 af[4], bfr[4];
#pragma unroll
    for (int mi = 0; mi < 4; ++mi)
      af[mi] = *(const short8*)(As + (wm * 64 + mi * 16 + l15) * 32 + quad * 8);
#pragma unroll
    for (int ni = 0; ni < 4; ++ni)
      bfr[ni] = *(const short8*)(Bs + (wn * 64 + ni * 16 + l15) * 32 + quad * 8);
#pragma unroll
    for (int mi = 0; mi < 4; ++mi)
#pragma unroll
      for (int ni = 0; ni < 4; ++ni)
        acc[mi][ni] = __builtin_amdgcn_mfma_f32_16x16x32_bf16(af[mi], bfr[ni], acc[mi][ni], 0, 0, 0);
    __syncthreads();
  }

  // Epilogue: bias + store bf16 into [b,h,s,hd]
#pragma unroll
  for (int ni = 0; ni < 4; ++ni) {
    int n = nBase + wn * 64 + ni * 16 + l15;
    float bv = bias[n];
    int h = n >> 6, hd = n & 63;
#pragma unroll
    for (int mi = 0; mi < 4; ++mi) {
      int m0 = mBase + wm * 64 + mi * 16 + quad * 4;
#pragma unroll
      for (int r = 0; r < 4; ++r) {
        int m = m0 + r;
        int bb = m >> 11, s = m & 2047;
        out[((bb * 16 + h) * 2048 + s) * 64 + hd] = f2bf(acc[mi][ni][r] + bv);
      }
    }
  }
}

// ---------------------------------------------------------------------------
// Flash-style attention with full-softmax denominator + anti-causal (k>=q)
// post-softmax numerator mask. Computes S^T = K*Q^T and O^T = V^T*P^T so the
// per-q softmax state lives on lane&15 and aligns with the O accumulator.
// Q-tile = 128 (1 block), K-tile = 128 per iteration, 4 waves x 32 q each.
// ---------------------------------------------------------------------------
__global__ __launch_bounds__(256) void attn_kernel(const ushort_t* __restrict__ qb,
                                                   const ushort_t* __restrict__ kb,
                                                   const ushort_t* __restrict__ vb,
                                                   ushort_t* __restrict__ zb) {
  __shared__ __align__(16) ushort_t Ks[128 * 72];   // [key][hd], stride 72 bf16
  __shared__ __align__(16) ushort_t Vt[64 * 136];   // [hd][key], stride 136 bf16
  __shared__ __align__(16) ushort_t Ps[128 * 136];  // [q][key],  stride 136 bf16
  const int bh   = blockIdx.y;
  const int qblk = blockIdx.x * 128;
  const int tid  = threadIdx.x;
  const int lane = tid & 63;
  const int w    = tid >> 6;
  const int quad = lane >> 4;
  const int l15  = lane & 15;
  const float cexp = 0.02209708691f * 1.44269504089f;  // (1/sqrt(2048)) * log2(e)

  const ushort_t* qpage = qb + (size_t)bh * (2048 * 64);
  const ushort_t* kpage = kb + (size_t)bh * (2048 * 64);
  const ushort_t* vpage = vb + (size_t)bh * (2048 * 64);

  // Preload Q fragments (constant across key tiles): q = qblk + w*32 + nb*16 + l15
  short8 qf[2][2];
#pragma unroll
  for (int nb = 0; nb < 2; ++nb) {
    int qg = qblk + w * 32 + nb * 16 + l15;
#pragma unroll
    for (int kd = 0; kd < 2; ++kd)
      qf[nb][kd] = *(const short8*)(qpage + qg * 64 + kd * 32 + quad * 8);
  }

  float m_run[2] = {-1e30f, -1e30f};
  float l_run[2] = {0.f, 0.f};
  f32x4 o[4][2] = {};  // O^T: [hd block 0..3][q block 0..1]

  const int qminw = qblk + w * 32;  // smallest q this wave owns

  for (int kt = 0; kt < 2048; kt += 128) {
    // ---- stage K tile [128][64] padded to stride 72 ----
#pragma unroll
    for (int p = 0; p < 4; ++p) {
      int c = p * 256 + tid;        // 0..1023
      int row = c >> 3;             // 0..127
      int col = (c & 7) * 8;        // hd offset (16B chunks)
      short8 kv = *(const short8*)(kpage + (kt + row) * 64 + col);
      *(short8*)(Ks + row * 72 + col) = kv;
    }
    // ---- stage V^T tile [64][128] padded to stride 136 (4x4 register transpose) ----
#pragma unroll
    for (int sb = 0; sb < 2; ++sb) {
      int id = sb * 256 + tid;      // 0..511
      int kg = id >> 4;             // key group 0..31
      int hg = id & 15;             // hd group 0..15
      us4 vr[4];
#pragma unroll
      for (int i = 0; i < 4; ++i)
        vr[i] = *(const us4*)(vpage + (kt + kg * 4 + i) * 64 + hg * 4);
#pragma unroll
      for (int j = 0; j < 4; ++j) {
        us4 t;
        t.u[0] = vr[0].u[j]; t.u[1] = vr[1].u[j]; t.u[2] = vr[2].u[j]; t.u[3] = vr[3].u[j];
        *(us4*)(Vt + (hg * 4 + j) * 136 + kg * 4) = t;
      }
    }
    __syncthreads();

    // ---- S^T = K * Q^T : st[mb][nb], key = mb*16+quad*4+r, q = nb*16+l15 ----
    f32x4 st[8][2] = {};
#pragma unroll
    for (int kd = 0; kd < 2; ++kd) {
#pragma unroll
      for (int mb = 0; mb < 8; ++mb) {
        short8 kf = *(const short8*)(Ks + (mb * 16 + l15) * 72 + kd * 32 + quad * 8);
#pragma unroll
        for (int nb = 0; nb < 2; ++nb)
          st[mb][nb] = __builtin_amdgcn_mfma_f32_16x16x32_bf16(kf, qf[nb][kd], st[mb][nb], 0, 0, 0);
      }
    }

    // ---- online softmax stats + masked P pack ----
#pragma unroll
    for (int nb = 0; nb < 2; ++nb) {
      float tm = -1e30f;
#pragma unroll
      for (int mb = 0; mb < 8; ++mb)
#pragma unroll
        for (int r = 0; r < 4; ++r) tm = fmaxf(tm, st[mb][nb][r]);
      tm = fmaxf(tm, __shfl_xor(tm, 16, 64));
      tm = fmaxf(tm, __shfl_xor(tm, 32, 64));
      float mn = fmaxf(m_run[nb], tm);
      float alpha = exp2f((m_run[nb] - mn) * cexp);
      int qg = qblk + w * 32 + nb * 16 + l15;
      float psum = 0.f;
#pragma unroll
      for (int mb = 0; mb < 8; ++mb) {
        us4 pk;
#pragma unroll
        for (int r = 0; r < 4; ++r) {
          float pe = exp2f((st[mb][nb][r] - mn) * cexp);
          psum += pe;  // denominator: ALL keys (mask is post-softmax)
          int keyg = kt + mb * 16 + quad * 4 + r;
          pk.u[r] = f2bf((keyg >= qg) ? pe : 0.f);  // numerator: keep k >= q
        }
        *(us4*)(Ps + (w * 32 + nb * 16 + l15) * 136 + mb * 16 + quad * 4) = pk;
      }
      psum += __shfl_xor(psum, 16, 64);
      psum += __shfl_xor(psum, 32, 64);
      l_run[nb] = l_run[nb] * alpha + psum;
      m_run[nb] = mn;
      // rescale O^T columns for this q block
#pragma unroll
      for (int mb = 0; mb < 4; ++mb)
#pragma unroll
        for (int r = 0; r < 4; ++r) o[mb][nb][r] *= alpha;
    }

    // ---- O^T += V^T * P^T (skip if whole tile is numerator-masked) ----
    if (kt + 127 >= qminw) {
#pragma unroll
      for (int kd = 0; kd < 4; ++kd) {
        short8 pf[2];
#pragma unroll
        for (int nb = 0; nb < 2; ++nb)
          pf[nb] = *(const short8*)(Ps + (w * 32 + nb * 16 + l15) * 136 + kd * 32 + quad * 8);
#pragma unroll
        for (int mb = 0; mb < 4; ++mb) {
          short8 vf = *(const short8*)(Vt + (mb * 16 + l15) * 136 + kd * 32 + quad * 8);
#pragma unroll
          for (int nb = 0; nb < 2; ++nb)
            o[mb][nb] = __builtin_amdgcn_mfma_f32_16x16x32_bf16(vf, pf[nb], o[mb][nb], 0, 0, 0);
        }
      }
    }
    __syncthreads();
  }

  // ---- epilogue: z[bh][q][hd] = O^T / l ----
#pragma unroll
  for (int nb = 0; nb < 2; ++nb) {
    float rl = 1.0f / l_run[nb];
    int qg = qblk + w * 32 + nb * 16 + l15;
#pragma unroll
    for (int mb = 0; mb < 4; ++mb)
#pragma unroll
      for (int r = 0; r < 4; ++r) {
        int hd = mb * 16 + quad * 4 + r;
        zb[((size_t)bh * 2048 + qg) * 64 + hd] = f2bf(o[mb][nb][r] * rl);
      }
  }
}

// ---------------------------------------------------------------------------
// Residual + LayerNorm with the reference's scrambled .view(b,s,-1) remap:
// out[srow][dcol] uses z[b][h=srow>>7][si=((srow&127)<<4)|(dcol>>6)][j=dcol&63]
// ---------------------------------------------------------------------------
__global__ __launch_bounds__(256) void ln_kernel(const float* __restrict__ emb,
                                                 const ushort_t* __restrict__ zb,
                                                 const float* __restrict__ gamma,
                                                 const float* __restrict__ beta,
                                                 float* __restrict__ out) {
  __shared__ float red[2][4];
  int row = blockIdx.x;          // 0..4095  (b*2048 + s)
  int b = row >> 11, s = row & 2047;
  int h = s >> 7;
  int siHi = (s & 127) << 4;
  int tid = threadIdx.x;
  int dcol = tid * 4;
  int si = siHi | (dcol >> 6);
  int j = dcol & 63;

  f32x4 e4 = *(const f32x4*)(emb + (size_t)row * 1024 + dcol);
  us4 z4 = *(const us4*)(zb + (((size_t)(b * 16 + h) * 2048 + si) * 64 + j));
  float x0 = e4[0] + bf2f(z4.u[0]);
  float x1 = e4[1] + bf2f(z4.u[1]);
  float x2 = e4[2] + bf2f(z4.u[2]);
  float x3 = e4[3] + bf2f(z4.u[3]);

  float sum = x0 + x1 + x2 + x3;
  float sq  = x0 * x0 + x1 * x1 + x2 * x2 + x3 * x3;
#pragma unroll
  for (int off = 1; off <= 32; off <<= 1) {
    sum += __shfl_xor(sum, off, 64);
    sq  += __shfl_xor(sq,  off, 64);
  }
  int wv = tid >> 6;
  if ((tid & 63) == 0) { red[0][wv] = sum; red[1][wv] = sq; }
  __syncthreads();
  float ts = red[0][0] + red[0][1] + red[0][2] + red[0][3];
  float tq = red[1][0] + red[1][1] + red[1][2] + red[1][3];
  float mu = ts * (1.0f / 1024.0f);
  float var = tq * (1.0f / 1024.0f) - mu * mu;
  float rsig = rsqrtf(var + 1e-5f);

  f32x4 g4 = *(const f32x4*)(gamma + dcol);
  f32x4 b4 = *(const f32x4*)(beta + dcol);
  f32x4 o4;
  o4[0] = (x0 - mu) * rsig * g4[0] + b4[0];
  o4[1] = (x1 - mu) * rsig * g4[1] + b4[1];
  o4[2] = (x2 - mu) * rsig * g4[2] + b4[2];
  o4[3] = (x3 - mu) * rsig * g4[3] + b4[3];
  *(f32x4*)(out + (size_t)row * 1024 + dcol) = o4;
}

// ---------------------------------------------------------------------------
extern "C" void kernel_launch(void* const* d_in, const int* in_sizes, int n_in,
                              void* d_out, int out_size, void* d_ws, size_t ws_size,
                              hipStream_t stream) {
  (void)in_sizes; (void)n_in; (void)out_size; (void)ws_size;
  const float* emb   = (const float*)d_in[0];
  const float* Wq    = (const float*)d_in[1];
  const float* bq    = (const float*)d_in[2];
  const float* Wk    = (const float*)d_in[3];
  const float* bk    = (const float*)d_in[4];
  const float* Wv    = (const float*)d_in[5];
  const float* bv    = (const float*)d_in[6];
  const float* gamma = (const float*)d_in[7];
  const float* beta  = (const float*)d_in[8];
  float* out = (float*)d_out;

  char* ws = (char*)d_ws;
  ushort_t* Xbf  = (ushort_t*)(ws);                    //  8,388,608 B
  ushort_t* Wqb  = (ushort_t*)(ws + 8388608);          //  2,097,152 B
  ushort_t* Wkb  = (ushort_t*)(ws + 10485760);
  ushort_t* Wvb  = (ushort_t*)(ws + 12582912);
  ushort_t* qbuf = (ushort_t*)(ws + 14680064);         //  8,388,608 B
  ushort_t* kbuf = (ushort_t*)(ws + 23068672);
  ushort_t* vbuf = (ushort_t*)(ws + 31457280);
  ushort_t* zbuf = (ushort_t*)(ws + 39845888);         //  8,388,608 B -> total 48,234,496 B

  cvt_kernel<<<4096, 256, 0, stream>>>(emb, Xbf, 4194304);
  cvt_kernel<<<1024, 256, 0, stream>>>(Wq, Wqb, 1048576);
  cvt_kernel<<<1024, 256, 0, stream>>>(Wk, Wkb, 1048576);
  cvt_kernel<<<1024, 256, 0, stream>>>(Wv, Wvb, 1048576);

  QkvArgs a;
  a.X = Xbf;
  a.W0 = Wqb; a.W1 = Wkb; a.W2 = Wvb;
  a.b0 = bq;  a.b1 = bk;  a.b2 = bv;
  a.o0 = qbuf; a.o1 = kbuf; a.o2 = vbuf;
  qkv_gemm<<<dim3(32, 8, 3), 256, 0, stream>>>(a);

  attn_kernel<<<dim3(16, 32), 256, 0, stream>>>(qbuf, kbuf, vbuf, zbuf);

  ln_kernel<<<4096, 256, 0, stream>>>(emb, zbuf, gamma, beta, out);
}